// Round 1
// baseline (865.191 us; speedup 1.0000x reference)
//
#include <hip/hip_runtime.h>
#include <hip/hip_bf16.h>
#include <cstdint>

// ---------------- types ----------------
typedef __attribute__((ext_vector_type(8))) _Float16 f16x8;
typedef __attribute__((ext_vector_type(4))) _Float16 f16x4;
typedef __attribute__((ext_vector_type(4))) float f32x4;

#define GOLDEN_CENTER_F 0.36787944117144233f
#define GOLDEN_LOWER_F  0.21231792754821915f
#define GOLDEN_UPPER_F  0.5f

static constexpr int Dm = 1024;   // model dim (K of gemm1, N of gemm2)
static constexpr int Im = 1024;   // expert inter dim (N of gemm1, K of gemm2)
static constexpr int NTOK = 8192; // B*T
static constexpr int NE = 8;

// async global->LDS, 16B per lane, LDS dest = wave-uniform base + lane*16
__device__ __forceinline__ void async16(const _Float16* g, _Float16* l) {
  __builtin_amdgcn_global_load_lds(
      (const __attribute__((address_space(1))) void*)g,
      (__attribute__((address_space(3))) void*)l,
      16, 0, 0);
}

// ---------------- routing (exact fp32) ----------------
__global__ void routing_kernel(const float* __restrict__ x, const float* __restrict__ Wr,
                               const float* __restrict__ temp, float* __restrict__ wts) {
  const int wave = threadIdx.x >> 6, lane = threadIdx.x & 63;
  const int t = blockIdx.x * 4 + wave;
  const float* xr = x + (size_t)t * Dm;
  float acc[NE] = {0.f,0.f,0.f,0.f,0.f,0.f,0.f,0.f};
  for (int d = lane; d < Dm; d += 64) {
    float xv = xr[d];
    const float* wr = Wr + (size_t)d * NE;
#pragma unroll
    for (int e = 0; e < NE; ++e) acc[e] += xv * wr[e];
  }
#pragma unroll
  for (int off = 32; off > 0; off >>= 1) {
#pragma unroll
    for (int e = 0; e < NE; ++e) acc[e] += __shfl_down(acc[e], off, 64);
  }
  if (lane == 0) {
    float T = temp[0];
    float w[NE], dist[NE];
    float wsum = 0.f;
#pragma unroll
    for (int e = 0; e < NE; ++e) {
      float inh = 1.f / (1.f + expf(-acc[e] / T));
      dist[e] = fabsf(inh - GOLDEN_CENTER_F);
      bool zone = (inh >= GOLDEN_LOWER_F) && (inh <= GOLDEN_UPPER_F);
      w[e] = zone ? expf(-dist[e] / 0.1f) : 0.f;
      wsum += w[e];
    }
    if (wsum < 1e-8f) {
      float fb[NE];
#pragma unroll
      for (int e = 0; e < NE; ++e) fb[e] = expf(-dist[e] / 0.3f);
      int i1 = 0;
      for (int e = 1; e < NE; ++e) if (fb[e] > fb[i1]) i1 = e;
      int i2 = (i1 == 0) ? 1 : 0;
      for (int e = 0; e < NE; ++e) if (e != i1 && fb[e] > fb[i2]) i2 = e;
      float s = fmaxf(fb[i1] + fb[i2], 1e-8f);
#pragma unroll
      for (int e = 0; e < NE; ++e) w[e] = 0.f;
      w[i1] = fb[i1] / s;
      w[i2] = fb[i2] / s;
      wsum = w[i1] + w[i2];
    }
    float inv = 1.f / fmaxf(wsum, 1e-8f);
#pragma unroll
    for (int e = 0; e < NE; ++e) wts[(size_t)t * NE + e] = w[e] * inv;
  }
}

// ---------------- x fp32 -> fp16 ----------------
__global__ void cvt_x_kernel(const float* __restrict__ x, _Float16* __restrict__ xb) {
  size_t i = ((size_t)blockIdx.x * 256 + threadIdx.x) * 4;
  float4 v = *(const float4*)(x + i);
  f16x4 o = {(_Float16)v.x, (_Float16)v.y, (_Float16)v.z, (_Float16)v.w};
  *(f16x4*)(xb + i) = o;
}

// ---------------- transpose+convert: src[e][r][c] f32 -> dst[e][c][r] f16 (1024x1024 per e) ----------------
__global__ void transpose_cvt_kernel(const float* __restrict__ src, _Float16* __restrict__ dst) {
  __shared__ float tile[32][33];
  const size_t base = (size_t)blockIdx.z * 1024 * 1024;
  const int r0 = blockIdx.y * 32, c0 = blockIdx.x * 32;
  const int tx = threadIdx.x & 31, ty = threadIdx.x >> 5; // ty 0..7
#pragma unroll
  for (int j = 0; j < 32; j += 8)
    tile[ty + j][tx] = src[base + (size_t)(r0 + ty + j) * 1024 + c0 + tx];
  __syncthreads();
#pragma unroll
  for (int j = 0; j < 32; j += 8)
    dst[base + (size_t)(c0 + ty + j) * 1024 + r0 + tx] = (_Float16)tile[tx][ty + j];
}

// ---------------- gemm1: h = silu(x@Wg) * (x@Wu), fused, per expert ----------------
// A: xb [8192,1024] f16 row-major. Bg/Bu: [1024(N=i), 1024(K=d)] f16 (B^T layout).
// H: [8192,1024] f16 out.
__global__ __launch_bounds__(256, 2) void gemm1_kernel(
    const _Float16* __restrict__ A, const _Float16* __restrict__ Bg,
    const _Float16* __restrict__ Bu, _Float16* __restrict__ H) {
  constexpr int K = Dm;
  __shared__ _Float16 As[128 * 32];
  __shared__ _Float16 Bgs[128 * 32];
  __shared__ _Float16 Bus[128 * 32];
  const int tid = threadIdx.x;
  const int wave = tid >> 6, lane = tid & 63;
  const int t0 = blockIdx.y * 128, n0 = blockIdx.x * 128;
  const int m_off = (wave & 1) * 64, n_off = (wave >> 1) * 64;

  f32x4 accg[4][4], accu[4][4];
#pragma unroll
  for (int i = 0; i < 4; ++i)
#pragma unroll
    for (int j = 0; j < 4; ++j) { accg[i][j] = (f32x4)0.f; accu[i][j] = (f32x4)0.f; }

  const int srow = lane >> 2;          // 0..15
  const int scol = (lane & 3) * 8;     // element offset in 32-wide K slab
  const _Float16* gA  = A  + (size_t)(t0 + wave * 32 + srow) * K + scol;
  const _Float16* gBg = Bg + (size_t)(n0 + wave * 32 + srow) * K + scol;
  const _Float16* gBu = Bu + (size_t)(n0 + wave * 32 + srow) * K + scol;
  _Float16* lA  = As  + (wave * 32) * 32;
  _Float16* lBg = Bgs + (wave * 32) * 32;
  _Float16* lBu = Bus + (wave * 32) * 32;

  const int fr = lane & 15, fq = lane >> 4;
  const int aoff = (m_off + fr) * 32 + fq * 8;
  const int boff = (n_off + fr) * 32 + fq * 8;

  for (int k0 = 0; k0 < K; k0 += 32) {
    __syncthreads();
    async16(gA + k0, lA);
    async16(gA + k0 + 16 * K, lA + 16 * 32);
    async16(gBg + k0, lBg);
    async16(gBg + k0 + 16 * K, lBg + 16 * 32);
    async16(gBu + k0, lBu);
    async16(gBu + k0 + 16 * K, lBu + 16 * 32);
    __syncthreads();

    f16x8 af[4], bgf[4], buf2[4];
#pragma unroll
    for (int i = 0; i < 4; ++i) {
      af[i]   = *(const f16x8*)(As  + aoff + i * 16 * 32);
      bgf[i]  = *(const f16x8*)(Bgs + boff + i * 16 * 32);
      buf2[i] = *(const f16x8*)(Bus + boff + i * 16 * 32);
    }
#pragma unroll
    for (int im = 0; im < 4; ++im)
#pragma unroll
      for (int in2 = 0; in2 < 4; ++in2) {
        accg[im][in2] = __builtin_amdgcn_mfma_f32_16x16x32_f16(af[im], bgf[in2], accg[im][in2], 0, 0, 0);
        accu[im][in2] = __builtin_amdgcn_mfma_f32_16x16x32_f16(af[im], buf2[in2], accu[im][in2], 0, 0, 0);
      }
  }

#pragma unroll
  for (int im = 0; im < 4; ++im)
#pragma unroll
    for (int in2 = 0; in2 < 4; ++in2)
#pragma unroll
      for (int r = 0; r < 4; ++r) {
        int t = t0 + m_off + im * 16 + fq * 4 + r;
        int c = n0 + n_off + in2 * 16 + fr;
        float g = accg[im][in2][r], u = accu[im][in2][r];
        float s = g / (1.f + __expf(-g));
        H[(size_t)t * Im + c] = (_Float16)(s * u);
      }
}

// ---------------- gemm2: out += w[t,e] * (h @ Wd_e) ----------------
// A: h [8192,1024] f16. B: WdT slice [1024(N=d), 1024(K=i)] f16. out: f32 [8192,1024].
__global__ __launch_bounds__(256, 2) void gemm2_kernel(
    const _Float16* __restrict__ A, const _Float16* __restrict__ B,
    const float* __restrict__ wts, float* __restrict__ out, int e, int accumulate) {
  constexpr int K = Im;
  __shared__ _Float16 As[128 * 32];
  __shared__ _Float16 Bs[128 * 32];
  __shared__ float wloc[128];
  const int tid = threadIdx.x;
  const int wave = tid >> 6, lane = tid & 63;
  const int t0 = blockIdx.y * 128, n0 = blockIdx.x * 128;
  const int m_off = (wave & 1) * 64, n_off = (wave >> 1) * 64;

  if (tid < 128) wloc[tid] = wts[(size_t)(t0 + tid) * NE + e];

  f32x4 acc[4][4];
#pragma unroll
  for (int i = 0; i < 4; ++i)
#pragma unroll
    for (int j = 0; j < 4; ++j) acc[i][j] = (f32x4)0.f;

  const int srow = lane >> 2;
  const int scol = (lane & 3) * 8;
  const _Float16* gA = A + (size_t)(t0 + wave * 32 + srow) * K + scol;
  const _Float16* gB = B + (size_t)(n0 + wave * 32 + srow) * K + scol;
  _Float16* lA = As + (wave * 32) * 32;
  _Float16* lB = Bs + (wave * 32) * 32;

  const int fr = lane & 15, fq = lane >> 4;
  const int aoff = (m_off + fr) * 32 + fq * 8;
  const int boff = (n_off + fr) * 32 + fq * 8;

  for (int k0 = 0; k0 < K; k0 += 32) {
    __syncthreads();
    async16(gA + k0, lA);
    async16(gA + k0 + 16 * K, lA + 16 * 32);
    async16(gB + k0, lB);
    async16(gB + k0 + 16 * K, lB + 16 * 32);
    __syncthreads();

    f16x8 af[4], bf[4];
#pragma unroll
    for (int i = 0; i < 4; ++i) {
      af[i] = *(const f16x8*)(As + aoff + i * 16 * 32);
      bf[i] = *(const f16x8*)(Bs + boff + i * 16 * 32);
    }
#pragma unroll
    for (int im = 0; im < 4; ++im)
#pragma unroll
      for (int in2 = 0; in2 < 4; ++in2)
        acc[im][in2] = __builtin_amdgcn_mfma_f32_16x16x32_f16(af[im], bf[in2], acc[im][in2], 0, 0, 0);
  }

#pragma unroll
  for (int im = 0; im < 4; ++im)
#pragma unroll
    for (int in2 = 0; in2 < 4; ++in2)
#pragma unroll
      for (int r = 0; r < 4; ++r) {
        int t = t0 + m_off + im * 16 + fq * 4 + r;
        int c = n0 + n_off + in2 * 16 + fr;
        float wv = wloc[m_off + im * 16 + fq * 4 + r];
        size_t idx = (size_t)t * Dm + c;
        float v = acc[im][in2][r] * wv;
        if (accumulate) out[idx] += v;
        else out[idx] = v;
      }
}

// ---------------- launch ----------------
extern "C" void kernel_launch(void* const* d_in, const int* in_sizes, int n_in,
                              void* d_out, int out_size, void* d_ws, size_t ws_size,
                              hipStream_t stream) {
  const float* x    = (const float*)d_in[0];
  const float* Wg   = (const float*)d_in[1];
  const float* Wu   = (const float*)d_in[2];
  const float* Wd   = (const float*)d_in[3];
  const float* Wr   = (const float*)d_in[4];
  const float* temp = (const float*)d_in[5];
  float* out = (float*)d_out;

  char* ws = (char*)d_ws;
  float* wts = (float*)ws;                                   // 256 KB
  _Float16* xb   = (_Float16*)(ws + (1 << 18));
  _Float16* WgT  = xb  + (size_t)NTOK * Dm;                  // [E,I,D]
  _Float16* WuT  = WgT + (size_t)NE * Dm * Im;
  _Float16* WdT  = WuT + (size_t)NE * Dm * Im;               // [E,D,I]
  _Float16* hbuf = WdT + (size_t)NE * Dm * Im;               // [8192, I]

  routing_kernel<<<NTOK / 4, 256, 0, stream>>>(x, Wr, temp, wts);
  cvt_x_kernel<<<(NTOK * Dm) / 1024, 256, 0, stream>>>(x, xb);
  transpose_cvt_kernel<<<dim3(32, 32, 8), 256, 0, stream>>>(Wg, WgT);
  transpose_cvt_kernel<<<dim3(32, 32, 8), 256, 0, stream>>>(Wu, WuT);
  transpose_cvt_kernel<<<dim3(32, 32, 8), 256, 0, stream>>>(Wd, WdT);

  for (int e = 0; e < NE; ++e) {
    const size_t eo = (size_t)e * Dm * Im;
    gemm1_kernel<<<dim3(Im / 128, NTOK / 128), 256, 0, stream>>>(xb, WgT + eo, WuT + eo, hbuf);
    gemm2_kernel<<<dim3(Dm / 128, NTOK / 128), 256, 0, stream>>>(hbuf, WdT + eo, wts, out, e, e > 0);
  }
}

// Round 2
// 569.721 us; speedup vs baseline: 1.5186x; 1.5186x over previous
//
#include <hip/hip_runtime.h>
#include <hip/hip_bf16.h>
#include <cstdint>

typedef __attribute__((ext_vector_type(8))) _Float16 f16x8;
typedef __attribute__((ext_vector_type(4))) _Float16 f16x4;
typedef __attribute__((ext_vector_type(4))) float f32x4;

#define GOLDEN_CENTER_F 0.36787944117144233f
#define GOLDEN_LOWER_F  0.21231792754821915f
#define GOLDEN_UPPER_F  0.5f

static constexpr int Dm = 1024;
static constexpr int Im = 1024;
static constexpr int NTOK = 8192;
static constexpr int NE = 8;

__device__ __forceinline__ void async16(const _Float16* g, _Float16* l) {
  __builtin_amdgcn_global_load_lds(
      (const __attribute__((address_space(1))) void*)g,
      (__attribute__((address_space(3))) void*)l,
      16, 0, 0);
}

// ---------------- routing (exact fp32) ----------------
__global__ void routing_kernel(const float* __restrict__ x, const float* __restrict__ Wr,
                               const float* __restrict__ temp, float* __restrict__ wts) {
  const int wave = threadIdx.x >> 6, lane = threadIdx.x & 63;
  const int t = blockIdx.x * 4 + wave;
  const float* xr = x + (size_t)t * Dm;
  float acc[NE] = {0.f,0.f,0.f,0.f,0.f,0.f,0.f,0.f};
  for (int d = lane; d < Dm; d += 64) {
    float xv = xr[d];
    const float* wr = Wr + (size_t)d * NE;
#pragma unroll
    for (int e = 0; e < NE; ++e) acc[e] += xv * wr[e];
  }
#pragma unroll
  for (int off = 32; off > 0; off >>= 1) {
#pragma unroll
    for (int e = 0; e < NE; ++e) acc[e] += __shfl_down(acc[e], off, 64);
  }
  if (lane == 0) {
    float T = temp[0];
    float w[NE], dist[NE];
    float wsum = 0.f;
#pragma unroll
    for (int e = 0; e < NE; ++e) {
      float inh = 1.f / (1.f + expf(-acc[e] / T));
      dist[e] = fabsf(inh - GOLDEN_CENTER_F);
      bool zone = (inh >= GOLDEN_LOWER_F) && (inh <= GOLDEN_UPPER_F);
      w[e] = zone ? expf(-dist[e] / 0.1f) : 0.f;
      wsum += w[e];
    }
    if (wsum < 1e-8f) {
      float fb[NE];
#pragma unroll
      for (int e = 0; e < NE; ++e) fb[e] = expf(-dist[e] / 0.3f);
      int i1 = 0;
      for (int e = 1; e < NE; ++e) if (fb[e] > fb[i1]) i1 = e;
      int i2 = (i1 == 0) ? 1 : 0;
      for (int e = 0; e < NE; ++e) if (e != i1 && fb[e] > fb[i2]) i2 = e;
      float s = fmaxf(fb[i1] + fb[i2], 1e-8f);
#pragma unroll
      for (int e = 0; e < NE; ++e) w[e] = 0.f;
      w[i1] = fb[i1] / s;
      w[i2] = fb[i2] / s;
      wsum = w[i1] + w[i2];
    }
    float inv = 1.f / fmaxf(wsum, 1e-8f);
#pragma unroll
    for (int e = 0; e < NE; ++e) wts[(size_t)t * NE + e] = w[e] * inv;
  }
}

// ---------------- compaction: per-expert active-token lists ----------------
__global__ void compact_kernel(const float* __restrict__ wts, int* __restrict__ tok,
                               float* __restrict__ wc, int* __restrict__ cnt) {
  const int e = blockIdx.x;
  const int tid = threadIdx.x;
  const int wave = tid >> 6, lane = tid & 63;
  __shared__ int wcnt[4];
  __shared__ int s_running;
  if (tid == 0) s_running = 0;
  __syncthreads();
  for (int base = 0; base < NTOK; base += 256) {
    int t = base + tid;
    float w = wts[(size_t)t * NE + e];
    bool act = w > 0.f;
    unsigned long long mask = __ballot(act);
    int prefix = __popcll(mask & ((1ull << lane) - 1ull));
    if (lane == 0) wcnt[wave] = __popcll(mask);
    __syncthreads();
    int wbase = 0;
    for (int i = 0; i < wave; ++i) wbase += wcnt[i];
    int run = s_running;
    if (act) {
      int pos = run + wbase + prefix;
      tok[(size_t)e * NTOK + pos] = t;
      wc[(size_t)e * NTOK + pos] = w;
    }
    __syncthreads();
    if (tid == 0) s_running = run + wcnt[0] + wcnt[1] + wcnt[2] + wcnt[3];
    __syncthreads();
  }
  int c = s_running;
  if (tid == 0) cnt[e] = c;
  int padded = (c + 127) & ~127;
  for (int p = c + tid; p < padded; p += 256) {
    tok[(size_t)e * NTOK + p] = 0;
    wc[(size_t)e * NTOK + p] = 0.f;
  }
}

// ---------------- x fp32 -> fp16 ----------------
__global__ void cvt_x_kernel(const float* __restrict__ x, _Float16* __restrict__ xb) {
  size_t i = ((size_t)blockIdx.x * 256 + threadIdx.x) * 4;
  float4 v = *(const float4*)(x + i);
  f16x4 o = {(_Float16)v.x, (_Float16)v.y, (_Float16)v.z, (_Float16)v.w};
  *(f16x4*)(xb + i) = o;
}

// ---------------- zero out ----------------
__global__ void zero_kernel(float4* __restrict__ p) {
  p[(size_t)blockIdx.x * 256 + threadIdx.x] = float4{0.f, 0.f, 0.f, 0.f};
}

// ---------------- transpose+convert all three weight tensors ----------------
__global__ void transpose_cvt_kernel(const float* __restrict__ Wg, const float* __restrict__ Wu,
                                     const float* __restrict__ Wd, _Float16* __restrict__ WgT,
                                     _Float16* __restrict__ WuT, _Float16* __restrict__ WdT) {
  __shared__ float tile[32][33];
  const int which = blockIdx.z >> 3;
  const int e = blockIdx.z & 7;
  const float* src = which == 0 ? Wg : which == 1 ? Wu : Wd;
  _Float16* dst = which == 0 ? WgT : which == 1 ? WuT : WdT;
  const size_t base = (size_t)e * 1024 * 1024;
  const int r0 = blockIdx.y * 32, c0 = blockIdx.x * 32;
  const int tx = threadIdx.x & 31, ty = threadIdx.x >> 5;
#pragma unroll
  for (int j = 0; j < 32; j += 8)
    tile[ty + j][tx] = src[base + (size_t)(r0 + ty + j) * 1024 + c0 + tx];
  __syncthreads();
#pragma unroll
  for (int j = 0; j < 32; j += 8)
    dst[base + (size_t)(c0 + ty + j) * 1024 + r0 + tx] = (_Float16)tile[tx][ty + j];
}

// ---------------- gemm1: h[e][r] = silu(x[tok]@Wg_e) * (x[tok]@Wu_e), gathered ----------------
__global__ __launch_bounds__(256, 2) void gemm1_kernel(
    const _Float16* __restrict__ A, const _Float16* __restrict__ BgAll,
    const _Float16* __restrict__ BuAll, const int* __restrict__ tok,
    const int* __restrict__ cnt, _Float16* __restrict__ hbuf) {
  constexpr int K = Dm;
  const int e = blockIdx.z;
  const int r0 = blockIdx.y * 128;
  if (r0 >= cnt[e]) return;
  const int n0 = blockIdx.x * 128;
  const _Float16* Bg = BgAll + (size_t)e * Dm * Im;
  const _Float16* Bu = BuAll + (size_t)e * Dm * Im;
  _Float16* H = hbuf + (size_t)e * NTOK * Im;
  const int* tk = tok + (size_t)e * NTOK;

  __shared__ _Float16 As[128 * 32];
  __shared__ _Float16 Bgs[128 * 32];
  __shared__ _Float16 Bus[128 * 32];
  const int tid = threadIdx.x;
  const int wave = tid >> 6, lane = tid & 63;
  const int m_off = (wave & 1) * 64, n_off = (wave >> 1) * 64;

  f32x4 accg[4][4], accu[4][4];
#pragma unroll
  for (int i = 0; i < 4; ++i)
#pragma unroll
    for (int j = 0; j < 4; ++j) { accg[i][j] = (f32x4)0.f; accu[i][j] = (f32x4)0.f; }

  const int srow = lane >> 2;
  const int scol = (lane & 3) * 8;
  const int ridx = r0 + wave * 32 + srow;
  const int tA0 = tk[ridx];
  const int tA1 = tk[ridx + 16];
  const _Float16* gA0 = A + (size_t)tA0 * K + scol;
  const _Float16* gA1 = A + (size_t)tA1 * K + scol;
  const _Float16* gBg = Bg + (size_t)(n0 + wave * 32 + srow) * K + scol;
  const _Float16* gBu = Bu + (size_t)(n0 + wave * 32 + srow) * K + scol;
  _Float16* lA  = As  + (wave * 32) * 32;
  _Float16* lBg = Bgs + (wave * 32) * 32;
  _Float16* lBu = Bus + (wave * 32) * 32;

  const int fr = lane & 15, fq = lane >> 4;
  const int aoff = (m_off + fr) * 32 + fq * 8;
  const int boff = (n_off + fr) * 32 + fq * 8;

  for (int k0 = 0; k0 < K; k0 += 32) {
    __syncthreads();
    async16(gA0 + k0, lA);
    async16(gA1 + k0, lA + 16 * 32);
    async16(gBg + k0, lBg);
    async16(gBg + k0 + 16 * K, lBg + 16 * 32);
    async16(gBu + k0, lBu);
    async16(gBu + k0 + 16 * K, lBu + 16 * 32);
    __syncthreads();

    f16x8 af[4], bgf[4], buf2[4];
#pragma unroll
    for (int i = 0; i < 4; ++i) {
      af[i]   = *(const f16x8*)(As  + aoff + i * 16 * 32);
      bgf[i]  = *(const f16x8*)(Bgs + boff + i * 16 * 32);
      buf2[i] = *(const f16x8*)(Bus + boff + i * 16 * 32);
    }
#pragma unroll
    for (int im = 0; im < 4; ++im)
#pragma unroll
      for (int in2 = 0; in2 < 4; ++in2) {
        accg[im][in2] = __builtin_amdgcn_mfma_f32_16x16x32_f16(af[im], bgf[in2], accg[im][in2], 0, 0, 0);
        accu[im][in2] = __builtin_amdgcn_mfma_f32_16x16x32_f16(af[im], buf2[in2], accu[im][in2], 0, 0, 0);
      }
  }

#pragma unroll
  for (int im = 0; im < 4; ++im)
#pragma unroll
    for (int in2 = 0; in2 < 4; ++in2)
#pragma unroll
      for (int r = 0; r < 4; ++r) {
        int row = r0 + m_off + im * 16 + fq * 4 + r;
        int c = n0 + n_off + in2 * 16 + fr;
        float g = accg[im][in2][r], u = accu[im][in2][r];
        float s = g / (1.f + __expf(-g));
        H[(size_t)row * Im + c] = (_Float16)(s * u);
      }
}

// ---------------- gemm2: out[tok[r]] += w[r] * (h[e][r] @ Wd_e) ----------------
__global__ __launch_bounds__(256, 2) void gemm2_kernel(
    const _Float16* __restrict__ hbuf, const _Float16* __restrict__ BAll,
    const int* __restrict__ tok, const float* __restrict__ wc,
    const int* __restrict__ cnt, float* __restrict__ out) {
  constexpr int K = Im;
  const int e = blockIdx.z;
  const int r0 = blockIdx.y * 128;
  if (r0 >= cnt[e]) return;
  const int n0 = blockIdx.x * 128;
  const _Float16* A = hbuf + (size_t)e * NTOK * Im;
  const _Float16* B = BAll + (size_t)e * Im * Dm;

  __shared__ _Float16 As[128 * 32];
  __shared__ _Float16 Bs[128 * 32];
  __shared__ float wloc[128];
  __shared__ int tloc[128];
  const int tid = threadIdx.x;
  const int wave = tid >> 6, lane = tid & 63;
  const int m_off = (wave & 1) * 64, n_off = (wave >> 1) * 64;

  if (tid < 128) {
    wloc[tid] = wc[(size_t)e * NTOK + r0 + tid];
    tloc[tid] = tok[(size_t)e * NTOK + r0 + tid];
  }

  f32x4 acc[4][4];
#pragma unroll
  for (int i = 0; i < 4; ++i)
#pragma unroll
    for (int j = 0; j < 4; ++j) acc[i][j] = (f32x4)0.f;

  const int srow = lane >> 2;
  const int scol = (lane & 3) * 8;
  const _Float16* gA = A + (size_t)(r0 + wave * 32 + srow) * K + scol;
  const _Float16* gB = B + (size_t)(n0 + wave * 32 + srow) * K + scol;
  _Float16* lA = As + (wave * 32) * 32;
  _Float16* lB = Bs + (wave * 32) * 32;

  const int fr = lane & 15, fq = lane >> 4;
  const int aoff = (m_off + fr) * 32 + fq * 8;
  const int boff = (n_off + fr) * 32 + fq * 8;

  for (int k0 = 0; k0 < K; k0 += 32) {
    __syncthreads();
    async16(gA + k0, lA);
    async16(gA + k0 + 16 * K, lA + 16 * 32);
    async16(gB + k0, lB);
    async16(gB + k0 + 16 * K, lB + 16 * 32);
    __syncthreads();

    f16x8 af[4], bf[4];
#pragma unroll
    for (int i = 0; i < 4; ++i) {
      af[i] = *(const f16x8*)(As + aoff + i * 16 * 32);
      bf[i] = *(const f16x8*)(Bs + boff + i * 16 * 32);
    }
#pragma unroll
    for (int im = 0; im < 4; ++im)
#pragma unroll
      for (int in2 = 0; in2 < 4; ++in2)
        acc[im][in2] = __builtin_amdgcn_mfma_f32_16x16x32_f16(af[im], bf[in2], acc[im][in2], 0, 0, 0);
  }
  __syncthreads();

#pragma unroll
  for (int im = 0; im < 4; ++im)
#pragma unroll
    for (int in2 = 0; in2 < 4; ++in2)
#pragma unroll
      for (int r = 0; r < 4; ++r) {
        int row = m_off + im * 16 + fq * 4 + r;
        int t = tloc[row];
        float wv = wloc[row];
        int c = n0 + n_off + in2 * 16 + fr;
        atomicAdd(out + (size_t)t * Dm + c, acc[im][in2][r] * wv);
      }
}

// ---------------- launch ----------------
extern "C" void kernel_launch(void* const* d_in, const int* in_sizes, int n_in,
                              void* d_out, int out_size, void* d_ws, size_t ws_size,
                              hipStream_t stream) {
  const float* x    = (const float*)d_in[0];
  const float* Wg   = (const float*)d_in[1];
  const float* Wu   = (const float*)d_in[2];
  const float* Wd   = (const float*)d_in[3];
  const float* Wr   = (const float*)d_in[4];
  const float* temp = (const float*)d_in[5];
  float* out = (float*)d_out;

  char* ws = (char*)d_ws;
  float* wts = (float*)ws;                                     // 256 KB
  int*   tok = (int*)(ws + (1 << 18));                         // 256 KB
  float* wc  = (float*)(ws + 2 * (1 << 18));                   // 256 KB
  int*   cnt = (int*)(ws + 3 * (1 << 18));                     // 256 B
  _Float16* xb  = (_Float16*)(ws + 3 * (1 << 18) + 4096);
  _Float16* WgT = xb  + (size_t)NTOK * Dm;
  _Float16* WuT = WgT + (size_t)NE * Dm * Im;
  _Float16* WdT = WuT + (size_t)NE * Dm * Im;
  _Float16* hbuf = WdT + (size_t)NE * Dm * Im;                 // worst case 128 MB

  routing_kernel<<<NTOK / 4, 256, 0, stream>>>(x, Wr, temp, wts);
  compact_kernel<<<NE, 256, 0, stream>>>(wts, tok, wc, cnt);
  cvt_x_kernel<<<(NTOK * Dm) / 1024, 256, 0, stream>>>(x, xb);
  transpose_cvt_kernel<<<dim3(32, 32, 24), 256, 0, stream>>>(Wg, Wu, Wd, WgT, WuT, WdT);
  zero_kernel<<<(NTOK * Dm / 4) / 256, 256, 0, stream>>>((float4*)out);

  gemm1_kernel<<<dim3(Im / 128, NTOK / 128, NE), 256, 0, stream>>>(xb, WgT, WuT, tok, cnt, hbuf);
  gemm2_kernel<<<dim3(Dm / 128, NTOK / 128, NE), 256, 0, stream>>>(hbuf, WdT, tok, wc, cnt, out);
}

// Round 4
// 486.712 us; speedup vs baseline: 1.7776x; 1.1706x over previous
//
#include <hip/hip_runtime.h>
#include <hip/hip_bf16.h>
#include <cstdint>

typedef __attribute__((ext_vector_type(8))) _Float16 f16x8;
typedef __attribute__((ext_vector_type(4))) _Float16 f16x4;
typedef __attribute__((ext_vector_type(4))) float f32x4;

#define GOLDEN_CENTER_F 0.36787944117144233f
#define GOLDEN_LOWER_F  0.21231792754821915f
#define GOLDEN_UPPER_F  0.5f

static constexpr int Dm = 1024;
static constexpr int Im = 1024;
static constexpr int NTOK = 8192;
static constexpr int NE = 8;

__device__ __forceinline__ void async16(const _Float16* g, _Float16* l) {
  __builtin_amdgcn_global_load_lds(
      (const __attribute__((address_space(1))) void*)g,
      (__attribute__((address_space(3))) void*)l,
      16, 0, 0);
}

// ---------------- routing (exact fp32) ----------------
__global__ void routing_kernel(const float* __restrict__ x, const float* __restrict__ Wr,
                               const float* __restrict__ temp, float* __restrict__ wts) {
  const int wave = threadIdx.x >> 6, lane = threadIdx.x & 63;
  const int t = blockIdx.x * 4 + wave;
  const float* xr = x + (size_t)t * Dm;
  float acc[NE] = {0.f,0.f,0.f,0.f,0.f,0.f,0.f,0.f};
  for (int d = lane; d < Dm; d += 64) {
    float xv = xr[d];
    const float* wr = Wr + (size_t)d * NE;
#pragma unroll
    for (int e = 0; e < NE; ++e) acc[e] += xv * wr[e];
  }
#pragma unroll
  for (int off = 32; off > 0; off >>= 1) {
#pragma unroll
    for (int e = 0; e < NE; ++e) acc[e] += __shfl_down(acc[e], off, 64);
  }
  if (lane == 0) {
    float T = temp[0];
    float w[NE], dist[NE];
    float wsum = 0.f;
#pragma unroll
    for (int e = 0; e < NE; ++e) {
      float inh = 1.f / (1.f + expf(-acc[e] / T));
      dist[e] = fabsf(inh - GOLDEN_CENTER_F);
      bool zone = (inh >= GOLDEN_LOWER_F) && (inh <= GOLDEN_UPPER_F);
      w[e] = zone ? expf(-dist[e] / 0.1f) : 0.f;
      wsum += w[e];
    }
    if (wsum < 1e-8f) {
      float fb[NE];
#pragma unroll
      for (int e = 0; e < NE; ++e) fb[e] = expf(-dist[e] / 0.3f);
      int i1 = 0;
      for (int e = 1; e < NE; ++e) if (fb[e] > fb[i1]) i1 = e;
      int i2 = (i1 == 0) ? 1 : 0;
      for (int e = 0; e < NE; ++e) if (e != i1 && fb[e] > fb[i2]) i2 = e;
      float s = fmaxf(fb[i1] + fb[i2], 1e-8f);
#pragma unroll
      for (int e = 0; e < NE; ++e) w[e] = 0.f;
      w[i1] = fb[i1] / s;
      w[i2] = fb[i2] / s;
      wsum = w[i1] + w[i2];
    }
    float inv = 1.f / fmaxf(wsum, 1e-8f);
#pragma unroll
    for (int e = 0; e < NE; ++e) wts[(size_t)t * NE + e] = w[e] * inv;
  }
}

// ---------------- compaction: per-expert active-token lists + pos table ----------------
__global__ void compact_kernel(const float* __restrict__ wts, int* __restrict__ tok,
                               float* __restrict__ wc, int* __restrict__ cnt,
                               int* __restrict__ pos) {
  const int e = blockIdx.x;
  const int tid = threadIdx.x;
  const int wave = tid >> 6, lane = tid & 63;
  __shared__ int wcnt[4];
  __shared__ int s_running;
  if (tid == 0) s_running = 0;
  __syncthreads();
  for (int base = 0; base < NTOK; base += 256) {
    int t = base + tid;
    float w = wts[(size_t)t * NE + e];
    bool act = w > 0.f;
    unsigned long long mask = __ballot(act);
    int prefix = __popcll(mask & ((1ull << lane) - 1ull));
    if (lane == 0) wcnt[wave] = __popcll(mask);
    __syncthreads();
    int wbase = 0;
    for (int i = 0; i < wave; ++i) wbase += wcnt[i];
    int run = s_running;
    int p = run + wbase + prefix;
    pos[(size_t)t * NE + e] = act ? p : -1;
    if (act) {
      tok[(size_t)e * NTOK + p] = t;
      wc[(size_t)e * NTOK + p] = w;
    }
    __syncthreads();
    if (tid == 0) s_running = run + wcnt[0] + wcnt[1] + wcnt[2] + wcnt[3];
    __syncthreads();
  }
  int c = s_running;
  if (tid == 0) cnt[e] = c;
  int padded = (c + 127) & ~127;
  for (int p = c + tid; p < padded; p += 256) {
    tok[(size_t)e * NTOK + p] = 0;
    wc[(size_t)e * NTOK + p] = 0.f;
  }
}

// ---------------- x fp32 -> fp16 ----------------
__global__ void cvt_x_kernel(const float* __restrict__ x, _Float16* __restrict__ xb) {
  size_t i = ((size_t)blockIdx.x * 256 + threadIdx.x) * 4;
  float4 v = *(const float4*)(x + i);
  f16x4 o = {(_Float16)v.x, (_Float16)v.y, (_Float16)v.z, (_Float16)v.w};
  *(f16x4*)(xb + i) = o;
}

// ---------------- transpose+convert all three weight tensors ----------------
__global__ void transpose_cvt_kernel(const float* __restrict__ Wg, const float* __restrict__ Wu,
                                     const float* __restrict__ Wd, _Float16* __restrict__ WgT,
                                     _Float16* __restrict__ WuT, _Float16* __restrict__ WdT) {
  __shared__ float tile[32][33];
  const int which = blockIdx.z >> 3;
  const int e = blockIdx.z & 7;
  const float* src = which == 0 ? Wg : which == 1 ? Wu : Wd;
  _Float16* dst = which == 0 ? WgT : which == 1 ? WuT : WdT;
  const size_t base = (size_t)e * 1024 * 1024;
  const int r0 = blockIdx.y * 32, c0 = blockIdx.x * 32;
  const int tx = threadIdx.x & 31, ty = threadIdx.x >> 5;
#pragma unroll
  for (int j = 0; j < 32; j += 8)
    tile[ty + j][tx] = src[base + (size_t)(r0 + ty + j) * 1024 + c0 + tx];
  __syncthreads();
#pragma unroll
  for (int j = 0; j < 32; j += 8)
    dst[base + (size_t)(c0 + ty + j) * 1024 + r0 + tx] = (_Float16)tile[tx][ty + j];
}

// ---------------- gemm1: h[z][r] = silu(x[tok]@Wg_e) * (x[tok]@Wu_e), gathered ----------------
__global__ __launch_bounds__(256, 2) void gemm1_kernel(
    const _Float16* __restrict__ A, const _Float16* __restrict__ BgAll,
    const _Float16* __restrict__ BuAll, const int* __restrict__ tok,
    const int* __restrict__ cnt, _Float16* __restrict__ hbuf, int ebase) {
  constexpr int K = Dm;
  const int z = blockIdx.z;
  const int e = ebase + z;
  const int r0 = blockIdx.y * 128;
  if (r0 >= cnt[e]) return;
  const int n0 = blockIdx.x * 128;
  const _Float16* Bg = BgAll + (size_t)e * Dm * Im;
  const _Float16* Bu = BuAll + (size_t)e * Dm * Im;
  _Float16* H = hbuf + (size_t)z * NTOK * Im;
  const int* tk = tok + (size_t)e * NTOK;

  __shared__ _Float16 As[128 * 32];
  __shared__ _Float16 Bgs[128 * 32];
  __shared__ _Float16 Bus[128 * 32];
  const int tid = threadIdx.x;
  const int wave = tid >> 6, lane = tid & 63;
  const int m_off = (wave & 1) * 64, n_off = (wave >> 1) * 64;

  f32x4 accg[4][4], accu[4][4];
#pragma unroll
  for (int i = 0; i < 4; ++i)
#pragma unroll
    for (int j = 0; j < 4; ++j) { accg[i][j] = (f32x4)0.f; accu[i][j] = (f32x4)0.f; }

  const int srow = lane >> 2;
  const int scol = (lane & 3) * 8;
  const int ridx = r0 + wave * 32 + srow;
  const int tA0 = tk[ridx];
  const int tA1 = tk[ridx + 16];
  const _Float16* gA0 = A + (size_t)tA0 * K + scol;
  const _Float16* gA1 = A + (size_t)tA1 * K + scol;
  const _Float16* gBg = Bg + (size_t)(n0 + wave * 32 + srow) * K + scol;
  const _Float16* gBu = Bu + (size_t)(n0 + wave * 32 + srow) * K + scol;
  _Float16* lA  = As  + (wave * 32) * 32;
  _Float16* lBg = Bgs + (wave * 32) * 32;
  _Float16* lBu = Bus + (wave * 32) * 32;

  const int fr = lane & 15, fq = lane >> 4;
  const int aoff = (m_off + fr) * 32 + fq * 8;
  const int boff = (n_off + fr) * 32 + fq * 8;

  for (int k0 = 0; k0 < K; k0 += 32) {
    __syncthreads();
    async16(gA0 + k0, lA);
    async16(gA1 + k0, lA + 16 * 32);
    async16(gBg + k0, lBg);
    async16(gBg + k0 + 16 * K, lBg + 16 * 32);
    async16(gBu + k0, lBu);
    async16(gBu + k0 + 16 * K, lBu + 16 * 32);
    __syncthreads();

    f16x8 af[4], bgf[4], buf2[4];
#pragma unroll
    for (int i = 0; i < 4; ++i) {
      af[i]   = *(const f16x8*)(As  + aoff + i * 16 * 32);
      bgf[i]  = *(const f16x8*)(Bgs + boff + i * 16 * 32);
      buf2[i] = *(const f16x8*)(Bus + boff + i * 16 * 32);
    }
#pragma unroll
    for (int im = 0; im < 4; ++im)
#pragma unroll
      for (int in2 = 0; in2 < 4; ++in2) {
        accg[im][in2] = __builtin_amdgcn_mfma_f32_16x16x32_f16(af[im], bgf[in2], accg[im][in2], 0, 0, 0);
        accu[im][in2] = __builtin_amdgcn_mfma_f32_16x16x32_f16(af[im], buf2[in2], accu[im][in2], 0, 0, 0);
      }
  }

#pragma unroll
  for (int im = 0; im < 4; ++im)
#pragma unroll
    for (int in2 = 0; in2 < 4; ++in2)
#pragma unroll
      for (int r = 0; r < 4; ++r) {
        int row = r0 + m_off + im * 16 + fq * 4 + r;
        int c = n0 + n_off + in2 * 16 + fr;
        float g = accg[im][in2][r], u = accu[im][in2][r];
        float s = g / (1.f + __expf(-g));
        H[(size_t)row * Im + c] = (_Float16)(s * u);
      }
}

// ---------------- gemm2: ebuf[z][row] = h[z][row] @ Wd_e  (unweighted, fp16, no atomics) ----------------
__global__ __launch_bounds__(256, 2) void gemm2_kernel(
    const _Float16* __restrict__ hbuf, const _Float16* __restrict__ BAll,
    const int* __restrict__ cnt, _Float16* __restrict__ ebuf, int ebase) {
  constexpr int K = Im;
  const int z = blockIdx.z;
  const int e = ebase + z;
  const int r0 = blockIdx.y * 128;
  if (r0 >= cnt[e]) return;
  const int n0 = blockIdx.x * 128;
  const _Float16* A = hbuf + (size_t)z * NTOK * Im;
  const _Float16* B = BAll + (size_t)e * Im * Dm;
  _Float16* Ez = ebuf + (size_t)z * NTOK * Dm;

  __shared__ _Float16 As[128 * 32];
  __shared__ _Float16 Bs[128 * 32];
  const int tid = threadIdx.x;
  const int wave = tid >> 6, lane = tid & 63;
  const int m_off = (wave & 1) * 64, n_off = (wave >> 1) * 64;

  f32x4 acc[4][4];
#pragma unroll
  for (int i = 0; i < 4; ++i)
#pragma unroll
    for (int j = 0; j < 4; ++j) acc[i][j] = (f32x4)0.f;

  const int srow = lane >> 2;
  const int scol = (lane & 3) * 8;
  const _Float16* gA = A + (size_t)(r0 + wave * 32 + srow) * K + scol;
  const _Float16* gB = B + (size_t)(n0 + wave * 32 + srow) * K + scol;
  _Float16* lA = As + (wave * 32) * 32;
  _Float16* lB = Bs + (wave * 32) * 32;

  const int fr = lane & 15, fq = lane >> 4;
  const int aoff = (m_off + fr) * 32 + fq * 8;
  const int boff = (n_off + fr) * 32 + fq * 8;

  for (int k0 = 0; k0 < K; k0 += 32) {
    __syncthreads();
    async16(gA + k0, lA);
    async16(gA + k0 + 16 * K, lA + 16 * 32);
    async16(gB + k0, lB);
    async16(gB + k0 + 16 * K, lB + 16 * 32);
    __syncthreads();

    f16x8 af[4], bf[4];
#pragma unroll
    for (int i = 0; i < 4; ++i) {
      af[i] = *(const f16x8*)(As + aoff + i * 16 * 32);
      bf[i] = *(const f16x8*)(Bs + boff + i * 16 * 32);
    }
#pragma unroll
    for (int im = 0; im < 4; ++im)
#pragma unroll
      for (int in2 = 0; in2 < 4; ++in2)
        acc[im][in2] = __builtin_amdgcn_mfma_f32_16x16x32_f16(af[im], bf[in2], acc[im][in2], 0, 0, 0);
  }

#pragma unroll
  for (int im = 0; im < 4; ++im)
#pragma unroll
    for (int in2 = 0; in2 < 4; ++in2)
#pragma unroll
      for (int r = 0; r < 4; ++r) {
        int row = m_off + im * 16 + fq * 4 + r;
        int c = n0 + n_off + in2 * 16 + fr;
        Ez[((size_t)(r0 + row)) * Dm + c] = (_Float16)acc[im][in2][r];
      }
}

// ---------------- combine: out[t] (=/+=) sum_{j<g} w[t,ebase+j] * ebuf[j][pos(t,ebase+j)] ----------------
__global__ void combine_kernel(const _Float16* __restrict__ ebuf, const int* __restrict__ pos,
                               const float* __restrict__ wts, float* __restrict__ out,
                               int ebase, int g, int accum) {
  const int t = blockIdx.x;
  __shared__ int sp[NE];
  __shared__ float sw[NE];
  if (threadIdx.x < g) {
    sp[threadIdx.x] = pos[(size_t)t * NE + ebase + threadIdx.x];
    sw[threadIdx.x] = wts[(size_t)t * NE + ebase + threadIdx.x];
  }
  __syncthreads();
  const int c = threadIdx.x * 4;
  float4 s;
  if (accum) s = *(const float4*)(out + (size_t)t * Dm + c);
  else s = float4{0.f, 0.f, 0.f, 0.f};
  for (int j = 0; j < g; ++j) {
    int p = sp[j];
    if (p >= 0) {
      float w = sw[j];
      f16x4 v = *(const f16x4*)(ebuf + ((size_t)j * NTOK + p) * Dm + c);
      s.x += w * (float)v[0];
      s.y += w * (float)v[1];
      s.z += w * (float)v[2];
      s.w += w * (float)v[3];
    }
  }
  *(float4*)(out + (size_t)t * Dm + c) = s;
}

// ---------------- launch ----------------
extern "C" void kernel_launch(void* const* d_in, const int* in_sizes, int n_in,
                              void* d_out, int out_size, void* d_ws, size_t ws_size,
                              hipStream_t stream) {
  const float* x    = (const float*)d_in[0];
  const float* Wg   = (const float*)d_in[1];
  const float* Wu   = (const float*)d_in[2];
  const float* Wd   = (const float*)d_in[3];
  const float* Wr   = (const float*)d_in[4];
  const float* temp = (const float*)d_in[5];
  float* out = (float*)d_out;

  char* ws = (char*)d_ws;
  size_t off = 0;
  auto carve = [&](size_t bytes) {
    char* p = ws + off;
    off = (off + bytes + 255) & ~(size_t)255;
    return p;
  };
  float* wts = (float*)carve((size_t)NTOK * NE * 4);
  int*   tok = (int*)  carve((size_t)NE * NTOK * 4);
  float* wc  = (float*)carve((size_t)NE * NTOK * 4);
  int*   pos = (int*)  carve((size_t)NTOK * NE * 4);
  int*   cnt = (int*)  carve(4096);
  _Float16* xb   = (_Float16*)carve((size_t)NTOK * Dm * 2);
  _Float16* WgT  = (_Float16*)carve((size_t)NE * Dm * Im * 2);
  _Float16* WuT  = (_Float16*)carve((size_t)NE * Dm * Im * 2);
  _Float16* WdT  = (_Float16*)carve((size_t)NE * Dm * Im * 2);
  const size_t fixed_off = off;
  const size_t per_expert = (size_t)NTOK * Im * 2 + (size_t)NTOK * Dm * 2; // hbuf+ebuf per expert
  // Pick the largest group size whose footprint fits the workspace.
  // Round-2 passed with ~193 MB used, so g=4 (193 MB) is guaranteed available.
  int g = (ws_size >= fixed_off + 8 * per_expert) ? 8 : 4;
  _Float16* hbuf = (_Float16*)carve((size_t)g * NTOK * Im * 2);
  _Float16* ebuf = (_Float16*)carve((size_t)g * NTOK * Dm * 2);

  routing_kernel<<<NTOK / 4, 256, 0, stream>>>(x, Wr, temp, wts);
  compact_kernel<<<NE, 256, 0, stream>>>(wts, tok, wc, cnt, pos);
  cvt_x_kernel<<<(NTOK * Dm) / 1024, 256, 0, stream>>>(x, xb);
  transpose_cvt_kernel<<<dim3(32, 32, 24), 256, 0, stream>>>(Wg, Wu, Wd, WgT, WuT, WdT);

  for (int e0 = 0; e0 < NE; e0 += g) {
    gemm1_kernel<<<dim3(Im / 128, NTOK / 128, g), 256, 0, stream>>>(xb, WgT, WuT, tok, cnt, hbuf, e0);
    gemm2_kernel<<<dim3(Dm / 128, NTOK / 128, g), 256, 0, stream>>>(hbuf, WdT, cnt, ebuf, e0);
    combine_kernel<<<NTOK, 256, 0, stream>>>(ebuf, pos, wts, out, e0, g, e0 > 0);
  }
}